// Round 3
// baseline (447.561 us; speedup 1.0000x reference)
//
#include <hip/hip_runtime.h>
#include <math.h>

// DIN-style sequence attention, MFMA version, R3.
// R2 -> R3: occupancy was the limiter (23%, 2 blocks/CU due to 69KB LDS).
// Drop the LDS K-tile entirely: MFMA A-fragments load straight from global
// fp32 (coalesced 128B segments), Phase D re-reads keys from global (L2-hot).
// LDS ~38KB -> 4 blocks/CU. Also: compiler bf16 cvt (v_cvt_pk), one fewer
// barrier, Weff build spread over all 256 threads.

constexpr int BATCH = 4096;
constexpr int T  = 200;
constexpr int H  = 64;     // D_IN = 4H = 256
constexpr int D1 = 80;
constexpr int D2 = 40;
constexpr int MROW = 208;  // 13 M-tiles of 16
constexpr int KS1 = 72;    // sWe row stride (64+8): bank-offset cycle-8 -> 2-way = free
constexpr int KS2 = 104;   // sW2T/sH1 row stride (96+8): covers k<=95 frags, 2-way banks

typedef __attribute__((ext_vector_type(8))) __bf16 bf16x8;
typedef __attribute__((ext_vector_type(4))) float  floatx4;

__device__ __forceinline__ float fsig(float x) {
    return __builtin_amdgcn_rcpf(1.0f + __expf(-x));
}
__device__ __forceinline__ bf16x8 pack8(float4 a, float4 b) {
    bf16x8 r;
    r[0] = (__bf16)a.x; r[1] = (__bf16)a.y; r[2] = (__bf16)a.z; r[3] = (__bf16)a.w;
    r[4] = (__bf16)b.x; r[5] = (__bf16)b.y; r[6] = (__bf16)b.z; r[7] = (__bf16)b.w;
    return r;
}
#define MFMA16(a, b, c) __builtin_amdgcn_mfma_f32_16x16x32_bf16((a), (b), (c), 0, 0, 0)

__global__ __launch_bounds__(256, 4) void din_mfma3(
    const float* __restrict__ q_g, const float* __restrict__ keys_g,
    const int* __restrict__ len_g, const float* __restrict__ W1,
    const float* __restrict__ b1g, const float* __restrict__ W2g,
    const float* __restrict__ b2g, const float* __restrict__ Wdg,
    const float* __restrict__ bdg, float* __restrict__ out)
{
    __shared__ __align__(16) __bf16 sWe[D1][KS1];     // WeffT[j][i]   11.5 KB
    __shared__ __align__(16) __bf16 sW2T[48][KS2];    // W2T[n][k]     10.0 KB
    __shared__ __align__(16) __bf16 sH1[4][16][KS2];  // per-wave H1   13.3 KB
    __shared__ __align__(16) float sS[MROW];
    __shared__ __align__(16) float sQ[H];
    __shared__ __align__(16) float sQp[D1];
    __shared__ __align__(16) float sB2[48];
    __shared__ __align__(16) float sWd[48];
    __shared__ __align__(16) float sRed[8];
    __shared__ __align__(16) float sPart[4][H];

    const int b    = blockIdx.x;
    const int tid  = threadIdx.x;
    const int lane = tid & 63;
    const int wave = tid >> 6;
    const int quad = lane >> 4;
    const int col  = lane & 15;
    const int len  = len_g[b];
    const float* __restrict__ kbase = keys_g + (size_t)b * T * H;

    // ---- Phase A1: stage q, W2T(bf16), biases; zero sH1 pad cols ----
    if (tid < H) sQ[tid] = q_g[b * H + tid];
    for (int idx = tid; idx < 48 * KS2; idx += 256) {
        const int n = idx / KS2, k = idx % KS2;
        sW2T[0][idx] = (n < D2 && k < D1) ? (__bf16)W2g[k * D2 + n] : (__bf16)0.f;
    }
    if (tid < 48) {
        sB2[tid] = (tid < D2) ? b2g[tid] : 0.f;
        sWd[tid] = (tid < D2) ? Wdg[tid] : 0.f;
    }
    for (int idx = tid; idx < 4 * 16 * 24; idx += 256) {   // H1 cols 80..103 = 0
        const int r = idx / 24, k = D1 + idx % 24;
        sH1[0][r][k] = (__bf16)0.f;
    }
    __syncthreads();

    // ---- layer-2 B fragments (ready now; overlaps A2 latency) ----
    bf16x8 B2f[9];
    #pragma unroll
    for (int n = 0; n < 3; ++n)
        #pragma unroll
        for (int ks = 0; ks < 3; ++ks)
            B2f[n * 3 + ks] = *(const bf16x8*)&sW2T[n * 16 + col][ks * 32 + quad * 8];

    // ---- Phase A2: per-b Weff (all 256 threads) + qpart (threads 0..79) ----
    for (int idx = tid; idx < D1 * H; idx += 256) {
        const int i = idx / D1, j = idx % D1;        // consecutive tid -> coalesced j
        const float w2 = W1[(128 + i) * D1 + j];
        sWe[j][i] = (__bf16)(W1[(64 + i) * D1 + j] - w2 + sQ[i] * W1[(192 + i) * D1 + j]);
    }
    if (tid < D1) {
        const int j = tid;
        float qp = b1g[j];
        #pragma unroll 8
        for (int i = 0; i < H; ++i)
            qp += sQ[i] * (W1[i * D1 + j] + W1[(128 + i) * D1 + j]);
        sQp[j] = qp;
    }
    __syncthreads();

    // ---- layer-1 B fragments ----
    bf16x8 B1f[10];
    #pragma unroll
    for (int n = 0; n < 5; ++n)
        #pragma unroll
        for (int ks = 0; ks < 2; ++ks)
            B1f[n * 2 + ks] = *(const bf16x8*)&sWe[n * 16 + col][ks * 32 + quad * 8];

    // ---- Phase B: MFMA scorer; waves own disjoint M-tiles, no barriers ----
    for (int mt = wave; mt < 13; mt += 4) {
        const int Mb = mt * 16;
        const int row = Mb + col;
        const bool inb = row < T;                     // only tile 12, col>=8 masked
        const float* kp = kbase + (size_t)(inb ? row : 0) * H + quad * 8;
        const float4 z4 = make_float4(0.f, 0.f, 0.f, 0.f);
        const float4 v0 = inb ? *(const float4*)(kp)      : z4;
        const float4 v1 = inb ? *(const float4*)(kp + 4)  : z4;
        const float4 v2 = inb ? *(const float4*)(kp + 32) : z4;
        const float4 v3 = inb ? *(const float4*)(kp + 36) : z4;
        const bf16x8 A0 = pack8(v0, v1);              // k = quad*8 + j
        const bf16x8 A1 = pack8(v2, v3);              // k = 32 + quad*8 + j

        // layer 1: S1 = K[16x64] @ Weff[64x80]
        #pragma unroll
        for (int n = 0; n < 5; ++n) {
            floatx4 acc = {0.f, 0.f, 0.f, 0.f};
            acc = MFMA16(A0, B1f[n * 2 + 0], acc);
            acc = MFMA16(A1, B1f[n * 2 + 1], acc);
            const float qpv = sQp[n * 16 + col];
            #pragma unroll
            for (int r = 0; r < 4; ++r)               // C/D: row=quad*4+r, col=lane&15
                sH1[wave][quad * 4 + r][n * 16 + col] = (__bf16)fsig(acc[r] + qpv);
        }
        // layer 2: S2 = H1[16x80] @ W2[80x40]
        const bf16x8 C0 = *(const bf16x8*)&sH1[wave][col][quad * 8];
        const bf16x8 C1 = *(const bf16x8*)&sH1[wave][col][32 + quad * 8];
        const bf16x8 C2 = *(const bf16x8*)&sH1[wave][col][64 + quad * 8];
        float sp0 = 0.f, sp1 = 0.f, sp2 = 0.f, sp3 = 0.f;
        #pragma unroll
        for (int n = 0; n < 3; ++n) {
            floatx4 acc = {0.f, 0.f, 0.f, 0.f};
            acc = MFMA16(C0, B2f[n * 3 + 0], acc);
            acc = MFMA16(C1, B2f[n * 3 + 1], acc);
            acc = MFMA16(C2, B2f[n * 3 + 2], acc);
            const float b2v = sB2[n * 16 + col];
            const float wdv = sWd[n * 16 + col];      // zero on pad cols
            sp0 += fsig(acc[0] + b2v) * wdv;
            sp1 += fsig(acc[1] + b2v) * wdv;
            sp2 += fsig(acc[2] + b2v) * wdv;
            sp3 += fsig(acc[3] + b2v) * wdv;
        }
        #pragma unroll
        for (int off = 1; off <= 8; off <<= 1) {      // reduce 16 cols within quad-group
            sp0 += __shfl_xor(sp0, off, 64);
            sp1 += __shfl_xor(sp1, off, 64);
            sp2 += __shfl_xor(sp2, off, 64);
            sp3 += __shfl_xor(sp3, off, 64);
        }
        if (col == 0) {
            sS[Mb + quad * 4 + 0] = sp0;
            sS[Mb + quad * 4 + 1] = sp1;
            sS[Mb + quad * 4 + 2] = sp2;
            sS[Mb + quad * 4 + 3] = sp3;
        }
    }
    __syncthreads();

    // ---- Phase C: block softmax over T (mask t>=len, scale 1/8) ----
    const int t = tid;
    float score = -INFINITY;
    if (t < T && t < len) score = sS[t] * 0.125f;
    float m = score;
    #pragma unroll
    for (int off = 32; off >= 1; off >>= 1)
        m = fmaxf(m, __shfl_xor(m, off, 64));
    if (lane == 0) sRed[wave] = m;
    __syncthreads();
    m = fmaxf(fmaxf(sRed[0], sRed[1]), fmaxf(sRed[2], sRed[3]));

    float e = 0.0f;
    if (t < T && t < len) e = __expf(score - m);
    float l = e;
    #pragma unroll
    for (int off = 32; off >= 1; off >>= 1)
        l += __shfl_xor(l, off, 64);
    if (lane == 0) sRed[4 + wave] = l;
    if (t < T) sS[t] = e;     // own slot: raw score already consumed by this thread
    __syncthreads();
    l = sRed[4] + sRed[5] + sRed[6] + sRed[7];
    const float inv_l = __builtin_amdgcn_rcpf(l);

    // ---- Phase D: out[b][h] = sum_t w_t * K[t][h] (global fp32, L2-hot) ----
    const int h = tid & 63;
    const int c = tid >> 6;                            // 4 chunks of 50 positions
    float p = 0.0f;
    for (int t2 = c * 50; t2 < c * 50 + 50; ++t2)
        p += sS[t2] * kbase[(size_t)t2 * H + h];       // coalesced 256B rows
    sPart[c][h] = p;
    __syncthreads();
    if (tid < H)
        out[b * H + tid] = (sPart[0][tid] + sPart[1][tid] + sPart[2][tid] + sPart[3][tid]) * inv_l;
}

extern "C" void kernel_launch(void* const* d_in, const int* in_sizes, int n_in,
                              void* d_out, int out_size, void* d_ws, size_t ws_size,
                              hipStream_t stream) {
    const float* q    = (const float*)d_in[0];
    const float* keys = (const float*)d_in[1];
    const int*   lens = (const int*)d_in[2];
    const float* W1   = (const float*)d_in[3];
    const float* b1   = (const float*)d_in[4];
    const float* W2   = (const float*)d_in[5];
    const float* b2   = (const float*)d_in[6];
    const float* Wd   = (const float*)d_in[7];
    const float* bd   = (const float*)d_in[8];
    float* outp = (float*)d_out;

    din_mfma3<<<BATCH, 256, 0, stream>>>(q, keys, lens, W1, b1, W2, b2, Wd, bd, outp);
}

// Round 4
// 413.357 us; speedup vs baseline: 1.0827x; 1.0827x over previous
//
#include <hip/hip_runtime.h>
#include <math.h>

// DIN-style sequence attention, R4.
// R3 -> R4: limiter was the per-block serial setup path (Weff/qpart/W2T
// staging + 6 barriers), not occupancy (R3 doubled occupancy, dur unchanged).
// Fix: batch-independent weights via augmented features S1 = qpart[b] +
// [k, q*k] @ [W1b-W1c; W1d] (K=128). Two tiny prep kernels build (a) bf16
// B-fragments in per-lane order and (b) qpart for all b, into d_ws. Main
// kernel: stage keys->LDS once (single HBM read, Phase B + D both hit LDS),
// 29 coalesced fragment loads, 13 MFMA tiles, softmax, weighted sum.

constexpr int BATCH = 4096;
constexpr int T  = 200;
constexpr int H  = 64;     // D_IN = 4H = 256
constexpr int D1 = 80;
constexpr int D2 = 40;
constexpr int MROW = 208;  // 13 M-tiles of 16
constexpr int KS1 = 72;    // sKb row stride (64+8 pad)
constexpr int KS2 = 104;   // sH1 row stride (96+8 pad)

// ws layout (bytes)
constexpr size_t WS_B1  = 0;          // 20 frags * 64 lanes * 16B = 20480
constexpr size_t WS_B2  = 20480;      // 9 frags * 64 lanes * 16B = 9216
constexpr size_t WS_B2V = 29696;      // 48 floats
constexpr size_t WS_WDV = 29888;      // 48 floats
constexpr size_t WS_QP  = 32768;      // 4096*80 floats = 1310720
constexpr size_t WS_TOTAL = WS_QP + (size_t)BATCH * D1 * 4;

typedef __attribute__((ext_vector_type(8))) __bf16 bf16x8;
typedef __attribute__((ext_vector_type(4))) float  floatx4;

__device__ __forceinline__ float fsig(float x) {
    return __builtin_amdgcn_rcpf(1.0f + __expf(-x));
}
#define MFMA16(a, b, c) __builtin_amdgcn_mfma_f32_16x16x32_bf16((a), (b), (c), 0, 0, 0)

// ---- prep 1: fragment-ordered bf16 weights (batch-independent) ----
// B1 covers K=128: k<64 -> W1b-W1c ; k>=64 -> W1d row (k-64).
// frag f = n*4+ks (n: 5 tiles of 16 outputs, ks: 4 segs of 32 k).
// lane (col=lane&15, quad=lane>>4) holds B[k=ks*32+quad*8+e][n*16+col].
__global__ void prep_weights(const float* __restrict__ W1,
                             const float* __restrict__ W2g,
                             const float* __restrict__ b2g,
                             const float* __restrict__ Wdg,
                             __bf16* __restrict__ wsB1, __bf16* __restrict__ wsB2,
                             float* __restrict__ wsB2v, float* __restrict__ wsWdv)
{
    const int tid = threadIdx.x;
    for (int u = tid; u < 20 * 64; u += 256) {
        const int f = u >> 6, lane = u & 63;
        const int n = f >> 2, ks = f & 3;
        const int col = lane & 15, quad = lane >> 4;
        const int j = n * 16 + col;
        __bf16 frag[8];
        #pragma unroll
        for (int e = 0; e < 8; ++e) {
            const int kk = ks * 32 + quad * 8 + e;
            const float v = (kk < 64)
                ? (W1[(64 + kk) * D1 + j] - W1[(128 + kk) * D1 + j])
                : W1[(128 + kk) * D1 + j];          // (192+(kk-64)) == 128+kk
            frag[e] = (__bf16)v;
        }
        *(bf16x8*)&wsB1[u * 8] = *(bf16x8*)frag;
    }
    for (int u = tid; u < 9 * 64; u += 256) {
        const int f = u >> 6, lane = u & 63;
        const int n3 = f / 3, ks3 = f % 3;
        const int col = lane & 15, quad = lane >> 4;
        const int j = n3 * 16 + col;
        __bf16 frag[8];
        #pragma unroll
        for (int e = 0; e < 8; ++e) {
            const int kk = ks3 * 32 + quad * 8 + e;
            frag[e] = (j < D2 && kk < D1) ? (__bf16)W2g[kk * D2 + j] : (__bf16)0.f;
        }
        *(bf16x8*)&wsB2[u * 8] = *(bf16x8*)frag;
    }
    if (tid < 48) {
        wsB2v[tid] = (tid < D2) ? b2g[tid] : 0.f;
        wsWdv[tid] = (tid < D2) ? Wdg[tid] : 0.f;
    }
}

// ---- prep 2: qpart[b][j] = b1[j] + q_b . (W1a + W1c), all b ----
__global__ __launch_bounds__(256) void prep_qpart(
    const float* __restrict__ q_g, const float* __restrict__ W1,
    const float* __restrict__ b1g, float* __restrict__ wsQp)
{
    __shared__ float sW1s[H * D1];   // 20 KB
    __shared__ float sq[16 * H];     // 4 KB
    const int tid = threadIdx.x;
    const int b0 = blockIdx.x * 16;
    for (int idx = tid; idx < H * D1; idx += 256) {
        const int i = idx / D1, j = idx % D1;
        sW1s[idx] = W1[i * D1 + j] + W1[(128 + i) * D1 + j];
    }
    for (int idx = tid; idx < 16 * H; idx += 256)
        sq[idx] = q_g[(size_t)b0 * H + idx];
    __syncthreads();
    for (int idx = tid; idx < 16 * D1; idx += 256) {
        const int bl = idx / D1, j = idx % D1;
        float acc = b1g[j];
        #pragma unroll 8
        for (int i = 0; i < H; ++i)
            acc += sq[bl * H + i] * sW1s[i * D1 + j];
        wsQp[(size_t)(b0 + bl) * D1 + j] = acc;
    }
}

// ---- main ----
template<bool QWS>
__global__ __launch_bounds__(256, 3) void din_main(
    const float* __restrict__ q_g, const float* __restrict__ keys_g,
    const int* __restrict__ len_g, const float* __restrict__ W1,
    const float* __restrict__ b1g,
    const __bf16* __restrict__ wsB1, const __bf16* __restrict__ wsB2,
    const float* __restrict__ wsB2v, const float* __restrict__ wsWdv,
    const float* __restrict__ wsQp, float* __restrict__ out)
{
    __shared__ __align__(16) __bf16 sKb[MROW][KS1];      // 29.9 KB, keys bf16
    __shared__ __align__(16) __bf16 sH1[4][16][KS2];     // 13.3 KB per-wave H1
    __shared__ __align__(16) float sS[MROW];
    __shared__ __align__(16) float sQp[D1];
    __shared__ __align__(16) float sB2[48];
    __shared__ __align__(16) float sWd[48];
    __shared__ __align__(16) float sQ[H];                // fallback only
    __shared__ __align__(16) float sRed[8];
    __shared__ __align__(16) float sPart[8][H];

    const int b    = blockIdx.x;
    const int tid  = threadIdx.x;
    const int lane = tid & 63;
    const int wave = tid >> 6;
    const int quad = lane >> 4;
    const int col  = lane & 15;
    const int len  = len_g[b];
    const float* __restrict__ qrow = q_g + (size_t)b * H;

    // ---- stage: keys -> LDS bf16; sQp; biases; sH1 pad cols ----
    const float4* keys4 = (const float4*)keys_g;
    for (int idx = tid; idx < MROW * 16; idx += 256) {
        const int row = idx >> 4, c4 = idx & 15;
        float4 v = make_float4(0.f, 0.f, 0.f, 0.f);
        if (row < T) v = keys4[((size_t)b * T + row) * 16 + c4];
        __bf16 tmp[4];
        tmp[0] = (__bf16)v.x; tmp[1] = (__bf16)v.y;
        tmp[2] = (__bf16)v.z; tmp[3] = (__bf16)v.w;
        *(float2*)&sKb[row][c4 * 4] = *(float2*)tmp;
    }
    if (QWS) { if (tid < D1) sQp[tid] = wsQp[(size_t)b * D1 + tid]; }
    else     { if (tid < H)  sQ[tid]  = qrow[tid]; }
    if (tid < 48) { sB2[tid] = wsB2v[tid]; sWd[tid] = wsWdv[tid]; }
    {   // zero sH1 k-cols 80..95 (read by layer-2 C2 frag)
        __bf16* h1f = &sH1[0][0][0];
        for (int idx = tid; idx < 64 * 16; idx += 256)
            h1f[(idx >> 4) * KS2 + 80 + (idx & 15)] = (__bf16)0.f;
    }

    // per-lane q values for the q*k fragments (L1 broadcast within quad)
    const float4 qa0 = *(const float4*)(qrow + quad * 8);
    const float4 qa1 = *(const float4*)(qrow + quad * 8 + 4);
    const float4 qb0 = *(const float4*)(qrow + 32 + quad * 8);
    const float4 qb1 = *(const float4*)(qrow + 32 + quad * 8 + 4);
    float qv[16] = {qa0.x, qa0.y, qa0.z, qa0.w, qa1.x, qa1.y, qa1.z, qa1.w,
                    qb0.x, qb0.y, qb0.z, qb0.w, qb1.x, qb1.y, qb1.z, qb1.w};

    // B fragments: coalesced 16B/lane, L2-broadcast across blocks
    bf16x8 B1f[20], B2f[9];
    #pragma unroll
    for (int f = 0; f < 20; ++f) B1f[f] = *(const bf16x8*)&wsB1[(f * 64 + lane) * 8];
    #pragma unroll
    for (int f = 0; f < 9; ++f)  B2f[f] = *(const bf16x8*)&wsB2[(f * 64 + lane) * 8];

    __syncthreads();

    if (!QWS) {   // inline qpart fallback (ws too small)
        if (tid < D1) {
            float qp = b1g[tid];
            #pragma unroll 8
            for (int i = 0; i < H; ++i)
                qp += sQ[i] * (W1[i * D1 + tid] + W1[(128 + i) * D1 + tid]);
            sQp[tid] = qp;
        }
        __syncthreads();
    }

    // ---- Phase B: MFMA scorer; waves own disjoint M-tiles, no barriers ----
    for (int mt = wave; mt < 13; mt += 4) {
        const int Mb = mt * 16;
        const __bf16* kr = &sKb[Mb + col][0];
        const bf16x8 A0 = *(const bf16x8*)&kr[quad * 8];        // k 0..31 seg
        const bf16x8 A1 = *(const bf16x8*)&kr[32 + quad * 8];   // k 32..63 seg
        bf16x8 A2, A3;                                          // q*k segs
        #pragma unroll
        for (int e = 0; e < 8; ++e) {
            A2[e] = (__bf16)(qv[e]     * (float)A0[e]);
            A3[e] = (__bf16)(qv[8 + e] * (float)A1[e]);
        }
        // layer 1: S1 = [k, q*k][16x128] @ W1eff[128x80]
        #pragma unroll
        for (int n = 0; n < 5; ++n) {
            floatx4 acc = {0.f, 0.f, 0.f, 0.f};
            acc = MFMA16(A0, B1f[n * 4 + 0], acc);
            acc = MFMA16(A1, B1f[n * 4 + 1], acc);
            acc = MFMA16(A2, B1f[n * 4 + 2], acc);
            acc = MFMA16(A3, B1f[n * 4 + 3], acc);
            const float qpv = sQp[n * 16 + col];
            #pragma unroll
            for (int r = 0; r < 4; ++r)             // C/D: row=quad*4+r, col
                sH1[wave][quad * 4 + r][n * 16 + col] = (__bf16)fsig(acc[r] + qpv);
        }
        // layer 2: S2 = H1[16x80] @ W2[80x40]
        const bf16x8 C0 = *(const bf16x8*)&sH1[wave][col][quad * 8];
        const bf16x8 C1 = *(const bf16x8*)&sH1[wave][col][32 + quad * 8];
        const bf16x8 C2 = *(const bf16x8*)&sH1[wave][col][64 + quad * 8];
        float sp0 = 0.f, sp1 = 0.f, sp2 = 0.f, sp3 = 0.f;
        #pragma unroll
        for (int n = 0; n < 3; ++n) {
            floatx4 acc = {0.f, 0.f, 0.f, 0.f};
            acc = MFMA16(C0, B2f[n * 3 + 0], acc);
            acc = MFMA16(C1, B2f[n * 3 + 1], acc);
            acc = MFMA16(C2, B2f[n * 3 + 2], acc);
            const float b2v = sB2[n * 16 + col];
            const float wdv = sWd[n * 16 + col];    // zero on pad cols
            sp0 += fsig(acc[0] + b2v) * wdv;
            sp1 += fsig(acc[1] + b2v) * wdv;
            sp2 += fsig(acc[2] + b2v) * wdv;
            sp3 += fsig(acc[3] + b2v) * wdv;
        }
        #pragma unroll
        for (int off = 1; off <= 8; off <<= 1) {    // reduce 16 cols in quad-group
            sp0 += __shfl_xor(sp0, off, 64);
            sp1 += __shfl_xor(sp1, off, 64);
            sp2 += __shfl_xor(sp2, off, 64);
            sp3 += __shfl_xor(sp3, off, 64);
        }
        if (col == 0) {
            sS[Mb + quad * 4 + 0] = sp0;
            sS[Mb + quad * 4 + 1] = sp1;
            sS[Mb + quad * 4 + 2] = sp2;
            sS[Mb + quad * 4 + 3] = sp3;
        }
    }
    __syncthreads();

    // ---- Phase C: block softmax over T (mask t>=len, scale 1/8) ----
    const int t = tid;
    float score = -INFINITY;
    if (t < T && t < len) score = sS[t] * 0.125f;
    float m = score;
    #pragma unroll
    for (int off = 32; off >= 1; off >>= 1)
        m = fmaxf(m, __shfl_xor(m, off, 64));
    if (lane == 0) sRed[wave] = m;
    __syncthreads();
    m = fmaxf(fmaxf(sRed[0], sRed[1]), fmaxf(sRed[2], sRed[3]));

    float e = 0.0f;
    if (t < T && t < len) e = __expf(score - m);
    float l = e;
    #pragma unroll
    for (int off = 32; off >= 1; off >>= 1)
        l += __shfl_xor(l, off, 64);
    if (lane == 0) sRed[4 + wave] = l;
    if (t < T) sS[t] = e;     // own slot: raw score already consumed here
    __syncthreads();
    l = sRed[4] + sRed[5] + sRed[6] + sRed[7];
    const float inv_l = __builtin_amdgcn_rcpf(l);

    // ---- Phase D: out[b][h] = sum_t w_t * K[t][h] from LDS bf16 ----
    const int h2i = tid & 31;          // column pair 2*h2i, 2*h2i+1
    const int c   = tid >> 5;          // 8 chunks of 25 positions
    float p0 = 0.f, p1 = 0.f;
    for (int t2 = c * 25; t2 < c * 25 + 25; ++t2) {
        const float w = sS[t2];
        const unsigned kk = *(const unsigned*)&sKb[t2][h2i * 2];
        union { unsigned u; float f; } lo, hi;
        lo.u = kk << 16; hi.u = kk & 0xffff0000u;
        p0 += w * lo.f;
        p1 += w * hi.f;
    }
    sPart[c][h2i * 2 + 0] = p0;
    sPart[c][h2i * 2 + 1] = p1;
    __syncthreads();
    if (tid < H) {
        float s = 0.f;
        #pragma unroll
        for (int cc = 0; cc < 8; ++cc) s += sPart[cc][tid];
        out[b * H + tid] = s * inv_l;
    }
}

extern "C" void kernel_launch(void* const* d_in, const int* in_sizes, int n_in,
                              void* d_out, int out_size, void* d_ws, size_t ws_size,
                              hipStream_t stream) {
    const float* q    = (const float*)d_in[0];
    const float* keys = (const float*)d_in[1];
    const int*   lens = (const int*)d_in[2];
    const float* W1   = (const float*)d_in[3];
    const float* b1   = (const float*)d_in[4];
    const float* W2   = (const float*)d_in[5];
    const float* b2   = (const float*)d_in[6];
    const float* Wd   = (const float*)d_in[7];
    const float* bd   = (const float*)d_in[8];
    float* outp = (float*)d_out;

    char* ws = (char*)d_ws;
    __bf16* wsB1 = (__bf16*)(ws + WS_B1);
    __bf16* wsB2 = (__bf16*)(ws + WS_B2);
    float* wsB2v = (float*)(ws + WS_B2V);
    float* wsWdv = (float*)(ws + WS_WDV);
    float* wsQp  = (float*)(ws + WS_QP);

    prep_weights<<<1, 256, 0, stream>>>(W1, W2, b2, Wd, wsB1, wsB2, wsB2v, wsWdv);
    const bool qws = ws_size >= WS_TOTAL;
    if (qws) {
        prep_qpart<<<BATCH / 16, 256, 0, stream>>>(q, W1, b1, wsQp);
        din_main<true><<<BATCH, 256, 0, stream>>>(q, keys, lens, W1, b1,
                                                  wsB1, wsB2, wsB2v, wsWdv, wsQp, outp);
    } else {
        din_main<false><<<BATCH, 256, 0, stream>>>(q, keys, lens, W1, b1,
                                                   wsB1, wsB2, wsB2v, wsWdv, wsQp, outp);
    }
}

// Round 5
// 402.936 us; speedup vs baseline: 1.1107x; 1.0259x over previous
//
#include <hip/hip_runtime.h>
#include <math.h>

// DIN-style sequence attention, R5.
// R4 -> R5: per-block wall was ~32us vs ~4us of work: bursty keys->LDS
// staging behind vmcnt(0)+barrier, plus compiler re-loading B-fragments
// mid-loop (VGPR_Count 84 < 116 needed). Fix: no keys LDS tile at all
// (A-frags from global fp32, Phase D re-reads global, L2-hot), B2 frags via
// LDS ds_read_b128 per tile (register relief), B1 frags resident. Waves
// stream barrier-free through Phase B.

constexpr int BATCH = 4096;
constexpr int T  = 200;
constexpr int H  = 64;     // D_IN = 4H = 256
constexpr int D1 = 80;
constexpr int D2 = 40;
constexpr int MROW = 208;  // 13 M-tiles of 16
constexpr int KS2 = 104;   // sH1 row stride (96+8 pad)

// ws layout (bytes)
constexpr size_t WS_B1  = 0;          // 20 frags * 64 lanes * 16B = 20480
constexpr size_t WS_B2  = 20480;      // 9 frags * 64 lanes * 16B = 9216
constexpr size_t WS_B2V = 29696;      // 48 floats
constexpr size_t WS_WDV = 29888;      // 48 floats
constexpr size_t WS_QP  = 32768;      // 4096*80 floats
constexpr size_t WS_TOTAL = WS_QP + (size_t)BATCH * D1 * 4;

typedef __attribute__((ext_vector_type(8))) __bf16 bf16x8;
typedef __attribute__((ext_vector_type(4))) float  floatx4;

__device__ __forceinline__ float fsig(float x) {
    return __builtin_amdgcn_rcpf(1.0f + __expf(-x));
}
#define MFMA16(a, b, c) __builtin_amdgcn_mfma_f32_16x16x32_bf16((a), (b), (c), 0, 0, 0)

// ---- prep 1: fragment-ordered bf16 weights (batch-independent) ----
// B1 covers K=128: k<64 -> W1b-W1c ; k>=64 -> W1d row (k-64).
// frag f = n*4+ks; lane (col=lane&15, quad=lane>>4) holds
// B[k=ks*32+quad*8+e][n*16+col].
__global__ void prep_weights(const float* __restrict__ W1,
                             const float* __restrict__ W2g,
                             const float* __restrict__ b2g,
                             const float* __restrict__ Wdg,
                             __bf16* __restrict__ wsB1, __bf16* __restrict__ wsB2,
                             float* __restrict__ wsB2v, float* __restrict__ wsWdv)
{
    const int gid = blockIdx.x * 256 + threadIdx.x;
    const int gstride = gridDim.x * 256;
    for (int u = gid; u < 20 * 64; u += gstride) {
        const int f = u >> 6, lane = u & 63;
        const int n = f >> 2, ks = f & 3;
        const int col = lane & 15, quad = lane >> 4;
        const int j = n * 16 + col;
        __bf16 frag[8];
        #pragma unroll
        for (int e = 0; e < 8; ++e) {
            const int kk = ks * 32 + quad * 8 + e;
            const float v = (kk < 64)
                ? (W1[(64 + kk) * D1 + j] - W1[(128 + kk) * D1 + j])
                : W1[(128 + kk) * D1 + j];          // (192+(kk-64)) == 128+kk
            frag[e] = (__bf16)v;
        }
        *(bf16x8*)&wsB1[u * 8] = *(bf16x8*)frag;
    }
    for (int u = gid; u < 9 * 64; u += gstride) {
        const int f = u >> 6, lane = u & 63;
        const int n3 = f / 3, ks3 = f % 3;
        const int col = lane & 15, quad = lane >> 4;
        const int j = n3 * 16 + col;
        __bf16 frag[8];
        #pragma unroll
        for (int e = 0; e < 8; ++e) {
            const int kk = ks3 * 32 + quad * 8 + e;
            frag[e] = (j < D2 && kk < D1) ? (__bf16)W2g[kk * D2 + j] : (__bf16)0.f;
        }
        *(bf16x8*)&wsB2[u * 8] = *(bf16x8*)frag;
    }
    if (gid < 48) {
        wsB2v[gid] = (gid < D2) ? b2g[gid] : 0.f;
        wsWdv[gid] = (gid < D2) ? Wdg[gid] : 0.f;
    }
}

// ---- prep 2: qpart[b][j] = b1[j] + q_b . (W1a + W1c), all b ----
__global__ __launch_bounds__(256) void prep_qpart(
    const float* __restrict__ q_g, const float* __restrict__ W1,
    const float* __restrict__ b1g, float* __restrict__ wsQp)
{
    __shared__ float sW1s[H * D1];   // 20 KB
    __shared__ float sq[16 * H];     // 4 KB
    const int tid = threadIdx.x;
    const int b0 = blockIdx.x * 16;
    for (int idx = tid; idx < H * D1; idx += 256) {
        const int i = idx / D1, j = idx % D1;
        sW1s[idx] = W1[i * D1 + j] + W1[(128 + i) * D1 + j];
    }
    for (int idx = tid; idx < 16 * H; idx += 256)
        sq[idx] = q_g[(size_t)b0 * H + idx];
    __syncthreads();
    for (int idx = tid; idx < 16 * D1; idx += 256) {
        const int bl = idx / D1, j = idx % D1;
        float acc = b1g[j];
        #pragma unroll 8
        for (int i = 0; i < H; ++i)
            acc += sq[bl * H + i] * sW1s[i * D1 + j];
        wsQp[(size_t)(b0 + bl) * D1 + j] = acc;
    }
}

// ---- main ----
template<bool QWS>
__global__ __launch_bounds__(256, 3) void din_main5(
    const float* __restrict__ q_g, const float* __restrict__ keys_g,
    const int* __restrict__ len_g, const float* __restrict__ W1,
    const float* __restrict__ b1g,
    const __bf16* __restrict__ wsB1, const __bf16* __restrict__ wsB2,
    const float* __restrict__ wsB2v, const float* __restrict__ wsWdv,
    const float* __restrict__ wsQp, float* __restrict__ out)
{
    __shared__ __align__(16) __bf16 sB2f[9 * 64 * 8];     // 9.2 KB frag-ordered
    __shared__ __align__(16) __bf16 sH1[4][16][KS2];      // 13.3 KB per-wave H1
    __shared__ __align__(16) float sS[MROW];
    __shared__ __align__(16) float sQp[D1];
    __shared__ __align__(16) float sQ[H];                 // fallback only
    __shared__ __align__(16) float sRed[8];
    __shared__ __align__(16) float sPart[4][H];

    const int b    = blockIdx.x;
    const int tid  = threadIdx.x;
    const int lane = tid & 63;
    const int wave = tid >> 6;
    const int quad = lane >> 4;
    const int col  = lane & 15;
    const int len  = len_g[b];
    const float* __restrict__ qrow  = q_g + (size_t)b * H;
    const float* __restrict__ kbase = keys_g + (size_t)b * T * H;

    // ---- stage B2 frags -> LDS (coalesced float4 copy) ----
    {
        const float4* src = (const float4*)wsB2;
        float4* dst = (float4*)sB2f;
        for (int idx = tid; idx < 9 * 64; idx += 256) dst[idx] = src[idx];
    }
    if (QWS) { if (tid < D1) sQp[tid] = wsQp[(size_t)b * D1 + tid]; }
    else     { if (tid < H)  sQ[tid]  = qrow[tid]; }

    // per-lane q values for the q*k fragments (quad-broadcast loads)
    const float4 qa0 = *(const float4*)(qrow + quad * 8);
    const float4 qa1 = *(const float4*)(qrow + quad * 8 + 4);
    const float4 qb0 = *(const float4*)(qrow + 32 + quad * 8);
    const float4 qb1 = *(const float4*)(qrow + 32 + quad * 8 + 4);
    float qv[16] = {qa0.x, qa0.y, qa0.z, qa0.w, qa1.x, qa1.y, qa1.z, qa1.w,
                    qb0.x, qb0.y, qb0.z, qb0.w, qb1.x, qb1.y, qb1.z, qb1.w};

    // per-lane layer-2 epilogue constants + qpart values
    float b2v[3], wdv[3], qpv[5];
    #pragma unroll
    for (int n = 0; n < 3; ++n) {
        b2v[n] = wsB2v[n * 16 + col];
        wdv[n] = wsWdv[n * 16 + col];
    }

    // B1 fragments resident in VGPRs (20 x 16B/lane, coalesced, L2-broadcast)
    bf16x8 B1f[20];
    #pragma unroll
    for (int f = 0; f < 20; ++f) B1f[f] = *(const bf16x8*)&wsB1[(f * 64 + lane) * 8];

    // zero own wave's sH1 pad cols 80..95 (wave-local, no barrier needed)
    {
        ushort4 z = {0, 0, 0, 0};
        *(ushort4*)&sH1[wave][lane >> 2][80 + (lane & 3) * 4] = z;
    }
    __syncthreads();   // sB2f + sQp (+ sQ) visible

    if (!QWS) {        // inline qpart fallback (ws too small)
        if (tid < D1) {
            float qp = b1g[tid];
            #pragma unroll 8
            for (int i = 0; i < H; ++i)
                qp += sQ[i] * (W1[i * D1 + tid] + W1[(128 + i) * D1 + tid]);
            sQp[tid] = qp;
        }
        __syncthreads();
    }
    #pragma unroll
    for (int n = 0; n < 5; ++n) qpv[n] = sQp[n * 16 + col];

    // ---- Phase B: MFMA scorer; waves stream, no barriers ----
    for (int mt = wave; mt < 13; mt += 4) {
        const int Mb = mt * 16;
        const int rowc = min(Mb + col, T - 1);       // clamp: tile 12 tail rows
        const float* kp = kbase + (size_t)rowc * H + quad * 8;
        const float4 v0 = *(const float4*)(kp);
        const float4 v1 = *(const float4*)(kp + 4);
        const float4 v2 = *(const float4*)(kp + 32);
        const float4 v3 = *(const float4*)(kp + 36);
        const float kf[16] = {v0.x, v0.y, v0.z, v0.w, v1.x, v1.y, v1.z, v1.w,
                              v2.x, v2.y, v2.z, v2.w, v3.x, v3.y, v3.z, v3.w};
        bf16x8 A0, A1, A2, A3;
        #pragma unroll
        for (int e = 0; e < 8; ++e) {
            A0[e] = (__bf16)kf[e];
            A1[e] = (__bf16)kf[8 + e];
            A2[e] = (__bf16)(qv[e] * kf[e]);          // q*k, k segment 0..31
            A3[e] = (__bf16)(qv[8 + e] * kf[8 + e]);  // q*k, k segment 32..63
        }
        // layer 1: S1 = [k, q*k][16x128] @ W1eff[128x80]
        #pragma unroll
        for (int n = 0; n < 5; ++n) {
            floatx4 acc = {0.f, 0.f, 0.f, 0.f};
            acc = MFMA16(A0, B1f[n * 4 + 0], acc);
            acc = MFMA16(A1, B1f[n * 4 + 1], acc);
            acc = MFMA16(A2, B1f[n * 4 + 2], acc);
            acc = MFMA16(A3, B1f[n * 4 + 3], acc);
            const float qpn = qpv[n];
            #pragma unroll
            for (int r = 0; r < 4; ++r)               // C/D: row=quad*4+r, col
                sH1[wave][quad * 4 + r][n * 16 + col] = (__bf16)fsig(acc[r] + qpn);
        }
        // layer 2: S2 = H1[16x80] @ W2[80x40]; A from own wave's LDS tile
        const bf16x8 C0 = *(const bf16x8*)&sH1[wave][col][quad * 8];
        const bf16x8 C1 = *(const bf16x8*)&sH1[wave][col][32 + quad * 8];
        const bf16x8 C2 = *(const bf16x8*)&sH1[wave][col][64 + quad * 8];
        float sp0 = 0.f, sp1 = 0.f, sp2 = 0.f, sp3 = 0.f;
        #pragma unroll
        for (int n = 0; n < 3; ++n) {
            floatx4 acc = {0.f, 0.f, 0.f, 0.f};
            #pragma unroll
            for (int ks = 0; ks < 3; ++ks) {          // B2 frags from LDS
                const bf16x8 Bf = *(const bf16x8*)&sB2f[((n * 3 + ks) * 64 + lane) * 8];
                acc = MFMA16(ks == 0 ? C0 : (ks == 1 ? C1 : C2), Bf, acc);
            }
            sp0 += fsig(acc[0] + b2v[n]) * wdv[n];
            sp1 += fsig(acc[1] + b2v[n]) * wdv[n];
            sp2 += fsig(acc[2] + b2v[n]) * wdv[n];
            sp3 += fsig(acc[3] + b2v[n]) * wdv[n];
        }
        #pragma unroll
        for (int off = 1; off <= 8; off <<= 1) {      // reduce 16 cols in quad-group
            sp0 += __shfl_xor(sp0, off, 64);
            sp1 += __shfl_xor(sp1, off, 64);
            sp2 += __shfl_xor(sp2, off, 64);
            sp3 += __shfl_xor(sp3, off, 64);
        }
        if (col == 0) {
            sS[Mb + quad * 4 + 0] = sp0;
            sS[Mb + quad * 4 + 1] = sp1;
            sS[Mb + quad * 4 + 2] = sp2;
            sS[Mb + quad * 4 + 3] = sp3;
        }
    }
    __syncthreads();

    // ---- Phase C: block softmax over T (mask t>=len, scale 1/8) ----
    const int t = tid;
    float score = -INFINITY;
    if (t < T && t < len) score = sS[t] * 0.125f;
    float m = score;
    #pragma unroll
    for (int off = 32; off >= 1; off >>= 1)
        m = fmaxf(m, __shfl_xor(m, off, 64));
    if (lane == 0) sRed[wave] = m;
    __syncthreads();
    m = fmaxf(fmaxf(sRed[0], sRed[1]), fmaxf(sRed[2], sRed[3]));

    float e = 0.0f;
    if (t < T && t < len) e = __expf(score - m);
    float l = e;
    #pragma unroll
    for (int off = 32; off >= 1; off >>= 1)
        l += __shfl_xor(l, off, 64);
    if (lane == 0) sRed[4 + wave] = l;
    if (t < T) sS[t] = e;     // own slot: raw score already consumed here
    __syncthreads();
    l = sRed[4] + sRed[5] + sRed[6] + sRed[7];
    const float inv_l = __builtin_amdgcn_rcpf(l);

    // ---- Phase D: out[b][h] = sum_t w_t * K[t][h] (global fp32, L2-hot) ----
    const int h = tid & 63;
    const int c = tid >> 6;                            // 4 chunks of 50
    float p = 0.0f;
    for (int t2 = c * 50; t2 < c * 50 + 50; ++t2)
        p += sS[t2] * kbase[(size_t)t2 * H + h];       // coalesced 256B rows
    sPart[c][h] = p;
    __syncthreads();
    if (tid < H)
        out[b * H + tid] = (sPart[0][tid] + sPart[1][tid] + sPart[2][tid] + sPart[3][tid]) * inv_l;
}

extern "C" void kernel_launch(void* const* d_in, const int* in_sizes, int n_in,
                              void* d_out, int out_size, void* d_ws, size_t ws_size,
                              hipStream_t stream) {
    const float* q    = (const float*)d_in[0];
    const float* keys = (const float*)d_in[1];
    const int*   lens = (const int*)d_in[2];
    const float* W1   = (const float*)d_in[3];
    const float* b1   = (const float*)d_in[4];
    const float* W2   = (const float*)d_in[5];
    const float* b2   = (const float*)d_in[6];
    const float* Wd   = (const float*)d_in[7];
    const float* bd   = (const float*)d_in[8];
    float* outp = (float*)d_out;

    char* ws = (char*)d_ws;
    __bf16* wsB1 = (__bf16*)(ws + WS_B1);
    __bf16* wsB2 = (__bf16*)(ws + WS_B2);
    float* wsB2v = (float*)(ws + WS_B2V);
    float* wsWdv = (float*)(ws + WS_WDV);
    float* wsQp  = (float*)(ws + WS_QP);

    prep_weights<<<8, 256, 0, stream>>>(W1, W2, b2, Wd, wsB1, wsB2, wsB2v, wsWdv);
    const bool qws = ws_size >= WS_TOTAL;
    if (qws) {
        prep_qpart<<<BATCH / 16, 256, 0, stream>>>(q, W1, b1, wsQp);
        din_main5<true><<<BATCH, 256, 0, stream>>>(q, keys, lens, W1, b1,
                                                   wsB1, wsB2, wsB2v, wsWdv, wsQp, outp);
    } else {
        din_main5<false><<<BATCH, 256, 0, stream>>>(q, keys, lens, W1, b1,
                                                    wsB1, wsB2, wsB2v, wsWdv, wsQp, outp);
    }
}